// Round 6
// baseline (84.450 us; speedup 1.0000x reference)
//
#include <hip/hip_runtime.h>
#include <cfloat>

// Chamfer L1, pred [B,N,3], gt [B,M,3] fp32, N==M==4096, B==4.
// R6: additive-pipe model (R0/R1/R5 all fit: time ≈ VALU + LDS, no overlap).
//     R5 pinned VALU to the 9.4us floor; now shrink LDS from 10.2us -> 1.9us:
//     - SoA LDS staging: 3 broadcast ds_read_b128 per 4 targets (vs 4 AoS)
//     - PTS=16 queries/thread: each staged target feeds 4x more VALU
//     - MC=128, NC=4096 -> grid 32x4x2 = 256 blocks = 1/CU
//     Inner arithmetic unchanged from R5 (asm-pinned 5.5 VALU/target).
//     ws 2MB->4MB (nmc=32): +0.7us traffic, -8us LDS. Predict partial ~11-13us.

constexpr int TPB = 256;
constexpr int PTS = 16;           // query points per thread
constexpr int NC  = TPB * PTS;    // 4096 queries per block (whole row)
constexpr int MC  = 128;          // targets staged in LDS per block

__global__ __launch_bounds__(TPB) void chamfer_partial_kernel(
    const float* __restrict__ pred, const float* __restrict__ gt,
    float* __restrict__ partial, int B, int N, int M) {
    const int dir = blockIdx.z;
    const int b   = blockIdx.y;
    const float* q = dir ? gt   : pred;
    const float* t = dir ? pred : gt;
    const int Nq   = dir ? M : N;
    const int Nt   = dir ? N : M;
    const int nchunks = Nq / NC;              // 1
    const int nc = blockIdx.x % nchunks;      // 0
    const int mc = blockIdx.x / nchunks;      // 0..Nt/MC-1 (31)

    __shared__ __align__(16) float ldsx[MC];  // SoA: 3 x 512 B
    __shared__ __align__(16) float ldsy[MC];
    __shared__ __align__(16) float ldsz[MC];

    // Stage target chunk (128 pts x 12 B) into LDS, AoS->SoA transpose.
    const float* tbase = t + ((size_t)b * Nt + (size_t)mc * MC) * 3;
    for (int i = threadIdx.x; i < MC * 3; i += TPB) {
        const int c = i % 3, p = i / 3;
        (c == 0 ? ldsx : c == 1 ? ldsy : ldsz)[p] = tbase[i];
    }
    __syncthreads();

    // 16 query points per thread, in registers.
    const float* qb = q + (size_t)b * Nq * 3;
    float px[PTS], py[PTS], pz[PTS], mn[PTS];
#pragma unroll
    for (int i = 0; i < PTS; ++i) {
        const int n = nc * NC + threadIdx.x + i * TPB;
        px[i] = qb[n * 3 + 0];
        py[i] = qb[n * 3 + 1];
        pz[i] = qb[n * 3 + 2];
        mn[i] = FLT_MAX;
    }

    // 4 targets per iter: 3 broadcast ds_read_b128; asm-pinned arithmetic
    // (5.5 VALU/target: 3 sub + 2 add|.| + 0.5 min3).
#pragma unroll 2
    for (int j = 0; j < MC; j += 4) {
        float4 gx = *(const float4*)&ldsx[j];
        float4 gy = *(const float4*)&ldsy[j];
        float4 gz = *(const float4*)&ldsz[j];
#pragma unroll
        for (int i = 0; i < PTS; ++i) {
            float dx0 = px[i] - gx.x, dy0 = py[i] - gy.x, dz0 = pz[i] - gz.x;
            float dx1 = px[i] - gx.y, dy1 = py[i] - gy.y, dz1 = pz[i] - gz.y;
            float dx2 = px[i] - gx.z, dy2 = py[i] - gy.z, dz2 = pz[i] - gz.z;
            float dx3 = px[i] - gx.w, dy3 = py[i] - gy.w, dz3 = pz[i] - gz.w;
            float s0, s1, s2, s3, d0, d1, d2, d3;
            asm("v_add_f32_e64 %0, |%1|, |%2|" : "=v"(s0) : "v"(dx0), "v"(dy0));
            asm("v_add_f32_e64 %0, %1, |%2|"   : "=v"(d0) : "v"(s0),  "v"(dz0));
            asm("v_add_f32_e64 %0, |%1|, |%2|" : "=v"(s1) : "v"(dx1), "v"(dy1));
            asm("v_add_f32_e64 %0, %1, |%2|"   : "=v"(d1) : "v"(s1),  "v"(dz1));
            asm("v_add_f32_e64 %0, |%1|, |%2|" : "=v"(s2) : "v"(dx2), "v"(dy2));
            asm("v_add_f32_e64 %0, %1, |%2|"   : "=v"(d2) : "v"(s2),  "v"(dz2));
            asm("v_add_f32_e64 %0, |%1|, |%2|" : "=v"(s3) : "v"(dx3), "v"(dy3));
            asm("v_add_f32_e64 %0, %1, |%2|"   : "=v"(d3) : "v"(s3),  "v"(dz3));
            asm("v_min3_f32 %0, %0, %1, %2"    : "+v"(mn[i]) : "v"(d0), "v"(d1));
            asm("v_min3_f32 %0, %0, %1, %2"    : "+v"(mn[i]) : "v"(d2), "v"(d3));
        }
    }

    // partial[mc][dir][b][n] — coalesced stores (N==M assumed for stride).
    float* outp = partial + (((size_t)mc * 2 + dir) * B + b) * N + nc * NC + threadIdx.x;
#pragma unroll
    for (int i = 0; i < PTS; ++i) outp[i * TPB] = mn[i];
}

__global__ __launch_bounds__(256) void chamfer_reduce_kernel(
    const float* __restrict__ partial, float* __restrict__ out,
    int Q, float inv) {
    const int qidx = blockIdx.x * 256 + threadIdx.x;
    float mn = FLT_MAX;
#pragma unroll
    for (int mc = 0; mc < 32; ++mc)   // nmc == 32 for N==M==4096, MC==128
        mn = fminf(mn, partial[(size_t)mc * Q + qidx]);
    float v = mn * inv;

    // wave-64 shuffle reduce, then cross-wave via LDS
    for (int off = 32; off > 0; off >>= 1) v += __shfl_down(v, off, 64);
    __shared__ float red[4];
    const int lane = threadIdx.x & 63, w = threadIdx.x >> 6;
    if (lane == 0) red[w] = v;
    __syncthreads();
    if (threadIdx.x == 0)
        atomicAdd(out, red[0] + red[1] + red[2] + red[3]);
}

extern "C" void kernel_launch(void* const* d_in, const int* in_sizes, int n_in,
                              void* d_out, int out_size, void* d_ws, size_t ws_size,
                              hipStream_t stream) {
    const float* pred = (const float*)d_in[0];
    const float* gt   = (const float*)d_in[1];
    float* out = (float*)d_out;

    const int B = 4;
    const int N = in_sizes[0] / (B * 3);   // 4096
    const int M = in_sizes[1] / (B * 3);   // 4096

    float* partial = (float*)d_ws;          // [32][2][B][N] floats = 4 MB
    const int Q = 2 * B * N;                // 32768

    hipMemsetAsync(out, 0, sizeof(float), stream);

    dim3 grid((N / NC) * (M / MC), B, 2);   // 32 x 4 x 2 = 256 blocks
    chamfer_partial_kernel<<<grid, TPB, 0, stream>>>(pred, gt, partial, B, N, M);

    // mean scale: 1/(B*N) for dir0, 1/(B*M) for dir1 — equal since N==M.
    chamfer_reduce_kernel<<<Q / 256, 256, 0, stream>>>(
        partial, out, Q, 1.0f / (float)(B * N));
}

// Round 7
// 73.078 us; speedup vs baseline: 1.1556x; 1.1556x over previous
//
#include <hip/hip_runtime.h>
#include <cfloat>

// Chamfer L1, pred [B,N,3], gt [B,M,3] fp32, N==M==4096, B==4.
// R7: model (fits R0/R1/R5/R6): at >=2 waves/SIMD, partial-kernel time is
//     ADDITIVE VALU + LDS-pipe; below 2 waves/SIMD latency explodes (R6).
//     So: keep EXACTLY 512 blocks (2/CU, 2 waves/SIMD) and shrink the LDS
//     term with SoA staging (3 broadcast ds_read_b128 per 4 targets):
//       R5: 2blk x 4w x 256 reads x 12cyc = 10.2us  ->  R7: 2x4x96x12 = 3.8us
//     VALU stays asm-pinned at the 9.4us floor (5.5 VALU/target:
//     3 sub + 2 add|.| + 0.5 min3). PTS=8, MC=128 -> grid 64x4x2 = 512.
//     ws 2->4MB (nmc=32): +0.9us traffic, -6.4us LDS.
// Kernel 2: min over 32 mc-chunks, scale, block-sum, one atomicAdd per block.

constexpr int TPB = 256;
constexpr int PTS = 8;            // query points per thread
constexpr int NC  = TPB * PTS;    // 2048 queries per block
constexpr int MC  = 128;          // targets staged in LDS per block

__global__ __launch_bounds__(TPB) void chamfer_partial_kernel(
    const float* __restrict__ pred, const float* __restrict__ gt,
    float* __restrict__ partial, int B, int N, int M) {
    const int dir = blockIdx.z;
    const int b   = blockIdx.y;
    const float* q = dir ? gt   : pred;
    const float* t = dir ? pred : gt;
    const int Nq   = dir ? M : N;
    const int Nt   = dir ? N : M;
    const int nchunks = Nq / NC;              // 2
    const int nc = blockIdx.x % nchunks;
    const int mc = blockIdx.x / nchunks;      // 0..Nt/MC-1 (31)

    __shared__ __align__(16) float ldsx[MC];  // SoA: 3 x 512 B
    __shared__ __align__(16) float ldsy[MC];
    __shared__ __align__(16) float ldsz[MC];

    // Stage target chunk (128 pts x 12 B) into LDS, AoS->SoA transpose.
    const float* tbase = t + ((size_t)b * Nt + (size_t)mc * MC) * 3;
    for (int i = threadIdx.x; i < MC * 3; i += TPB) {
        const int c = i % 3, p = i / 3;
        (c == 0 ? ldsx : c == 1 ? ldsy : ldsz)[p] = tbase[i];
    }
    __syncthreads();

    // 8 query points per thread, in registers.
    const float* qb = q + (size_t)b * Nq * 3;
    float px[PTS], py[PTS], pz[PTS], mn[PTS];
    int n[PTS];
#pragma unroll
    for (int i = 0; i < PTS; ++i) {
        n[i] = nc * NC + threadIdx.x + i * TPB;
        px[i] = qb[n[i] * 3 + 0];
        py[i] = qb[n[i] * 3 + 1];
        pz[i] = qb[n[i] * 3 + 2];
        mn[i] = FLT_MAX;
    }

    // 4 targets per iter: 3 broadcast ds_read_b128; asm-pinned arithmetic.
#pragma unroll 2
    for (int j = 0; j < MC; j += 4) {
        float4 gx = *(const float4*)&ldsx[j];
        float4 gy = *(const float4*)&ldsy[j];
        float4 gz = *(const float4*)&ldsz[j];
#pragma unroll
        for (int i = 0; i < PTS; ++i) {
            float dx0 = px[i] - gx.x, dy0 = py[i] - gy.x, dz0 = pz[i] - gz.x;
            float dx1 = px[i] - gx.y, dy1 = py[i] - gy.y, dz1 = pz[i] - gz.y;
            float dx2 = px[i] - gx.z, dy2 = py[i] - gy.z, dz2 = pz[i] - gz.z;
            float dx3 = px[i] - gx.w, dy3 = py[i] - gy.w, dz3 = pz[i] - gz.w;
            float s0, s1, s2, s3, d0, d1, d2, d3;
            asm("v_add_f32_e64 %0, |%1|, |%2|" : "=v"(s0) : "v"(dx0), "v"(dy0));
            asm("v_add_f32_e64 %0, %1, |%2|"   : "=v"(d0) : "v"(s0),  "v"(dz0));
            asm("v_add_f32_e64 %0, |%1|, |%2|" : "=v"(s1) : "v"(dx1), "v"(dy1));
            asm("v_add_f32_e64 %0, %1, |%2|"   : "=v"(d1) : "v"(s1),  "v"(dz1));
            asm("v_add_f32_e64 %0, |%1|, |%2|" : "=v"(s2) : "v"(dx2), "v"(dy2));
            asm("v_add_f32_e64 %0, %1, |%2|"   : "=v"(d2) : "v"(s2),  "v"(dz2));
            asm("v_add_f32_e64 %0, |%1|, |%2|" : "=v"(s3) : "v"(dx3), "v"(dy3));
            asm("v_add_f32_e64 %0, %1, |%2|"   : "=v"(d3) : "v"(s3),  "v"(dz3));
            asm("v_min3_f32 %0, %0, %1, %2"    : "+v"(mn[i]) : "v"(d0), "v"(d1));
            asm("v_min3_f32 %0, %0, %1, %2"    : "+v"(mn[i]) : "v"(d2), "v"(d3));
        }
    }

    // partial[mc][dir][b][n] — coalesced stores (N==M assumed for stride).
    float* outp = partial + (((size_t)mc * 2 + dir) * B + b) * N;
#pragma unroll
    for (int i = 0; i < PTS; ++i) outp[n[i]] = mn[i];
}

__global__ __launch_bounds__(256) void chamfer_reduce_kernel(
    const float* __restrict__ partial, float* __restrict__ out,
    int Q, float inv) {
    const int qidx = blockIdx.x * 256 + threadIdx.x;
    float mn = FLT_MAX;
#pragma unroll
    for (int mc = 0; mc < 32; ++mc)   // nmc == 32 for N==M==4096, MC==128
        mn = fminf(mn, partial[(size_t)mc * Q + qidx]);
    float v = mn * inv;

    // wave-64 shuffle reduce, then cross-wave via LDS
    for (int off = 32; off > 0; off >>= 1) v += __shfl_down(v, off, 64);
    __shared__ float red[4];
    const int lane = threadIdx.x & 63, w = threadIdx.x >> 6;
    if (lane == 0) red[w] = v;
    __syncthreads();
    if (threadIdx.x == 0)
        atomicAdd(out, red[0] + red[1] + red[2] + red[3]);
}

extern "C" void kernel_launch(void* const* d_in, const int* in_sizes, int n_in,
                              void* d_out, int out_size, void* d_ws, size_t ws_size,
                              hipStream_t stream) {
    const float* pred = (const float*)d_in[0];
    const float* gt   = (const float*)d_in[1];
    float* out = (float*)d_out;

    const int B = 4;
    const int N = in_sizes[0] / (B * 3);   // 4096
    const int M = in_sizes[1] / (B * 3);   // 4096

    float* partial = (float*)d_ws;          // [32][2][B][N] floats = 4 MB
    const int Q = 2 * B * N;                // 32768

    hipMemsetAsync(out, 0, sizeof(float), stream);

    dim3 grid((N / NC) * (M / MC), B, 2);   // 64 x 4 x 2 = 512 blocks
    chamfer_partial_kernel<<<grid, TPB, 0, stream>>>(pred, gt, partial, B, N, M);

    // mean scale: 1/(B*N) for dir0, 1/(B*M) for dir1 — equal since N==M.
    chamfer_reduce_kernel<<<Q / 256, 256, 0, stream>>>(
        partial, out, Q, 1.0f / (float)(B * N));
}

// Round 8
// 71.367 us; speedup vs baseline: 1.1833x; 1.0240x over previous
//
#include <hip/hip_runtime.h>
#include <cfloat>

// Chamfer L1, pred [B,N,3], gt [B,M,3] fp32, N==M==4096, B==4.
// R8: R7 structure (512 blocks = 2/CU, PTS=8, MC=128, SoA LDS, asm-pinned
//     5.5 VALU/target) measured 73.1us. Budget: fill 40 + overhead 13 +
//     reduce 2.5 + partial 17.5 (model floor 11.7 -> ~6us suspected lgkmcnt
//     stalls: LDS reads consumed immediately at 2 waves/SIMD).
//     Three changes:
//     (1) register-pipeline LDS reads: read iter j+1's three float4s
//         (branchless wrap index) BEFORE computing iter j -> lgkmcnt wait
//         sits behind 176 VALU ops instead of in front of them.
//     (2) hoist query global loads above LDS staging (overlap ~900cyc cold
//         latency with staging + barrier).
//     (3) drop the 4B memset dispatch: partial block (0,0,0) zero-inits out
//         (stream order covers reduce's atomicAdds). 3 -> 2 dispatches.

constexpr int TPB = 256;
constexpr int PTS = 8;            // query points per thread
constexpr int NC  = TPB * PTS;    // 2048 queries per block
constexpr int MC  = 128;          // targets staged in LDS per block

__global__ __launch_bounds__(TPB) void chamfer_partial_kernel(
    const float* __restrict__ pred, const float* __restrict__ gt,
    float* __restrict__ partial, float* __restrict__ out,
    int B, int N, int M) {
    const int dir = blockIdx.z;
    const int b   = blockIdx.y;
    const float* q = dir ? gt   : pred;
    const float* t = dir ? pred : gt;
    const int Nq   = dir ? M : N;
    const int Nt   = dir ? N : M;
    const int nchunks = Nq / NC;              // 2
    const int nc = blockIdx.x % nchunks;
    const int mc = blockIdx.x / nchunks;      // 0..Nt/MC-1 (31)

    // (3) in-kernel zero-init of the output accumulator (replaces memset).
    if (blockIdx.x == 0 && blockIdx.y == 0 && blockIdx.z == 0 && threadIdx.x == 0)
        *out = 0.0f;

    __shared__ __align__(16) float ldsx[MC];  // SoA: 3 x 512 B
    __shared__ __align__(16) float ldsy[MC];
    __shared__ __align__(16) float ldsz[MC];

    // (2) Query loads FIRST — their vmcnt wait lands after staging+barrier.
    const float* qb = q + (size_t)b * Nq * 3;
    float px[PTS], py[PTS], pz[PTS], mn[PTS];
    int n[PTS];
#pragma unroll
    for (int i = 0; i < PTS; ++i) {
        n[i] = nc * NC + threadIdx.x + i * TPB;
        px[i] = qb[n[i] * 3 + 0];
        py[i] = qb[n[i] * 3 + 1];
        pz[i] = qb[n[i] * 3 + 2];
        mn[i] = FLT_MAX;
    }

    // Stage target chunk (128 pts x 12 B) into LDS, AoS->SoA transpose.
    const float* tbase = t + ((size_t)b * Nt + (size_t)mc * MC) * 3;
    for (int i = threadIdx.x; i < MC * 3; i += TPB) {
        const int c = i % 3, p = i / 3;
        (c == 0 ? ldsx : c == 1 ? ldsy : ldsz)[p] = tbase[i];
    }
    __syncthreads();

    // (1) Register-pipelined j-loop: 4 targets per iter, 3 broadcast
    // ds_read_b128 for iter j+1 issued before iter j's 176 VALU ops.
    const float4* lx4 = (const float4*)ldsx;
    const float4* ly4 = (const float4*)ldsy;
    const float4* lz4 = (const float4*)ldsz;
    constexpr int NIT = MC / 4;               // 32
    float4 gx = lx4[0], gy = ly4[0], gz = lz4[0];
#pragma unroll 2
    for (int j4 = 0; j4 < NIT; ++j4) {
        const int jn = (j4 + 1) & (NIT - 1);  // branchless wrap (1 wasted read)
        float4 nx = lx4[jn], ny = ly4[jn], nz = lz4[jn];
#pragma unroll
        for (int i = 0; i < PTS; ++i) {
            float dx0 = px[i] - gx.x, dy0 = py[i] - gy.x, dz0 = pz[i] - gz.x;
            float dx1 = px[i] - gx.y, dy1 = py[i] - gy.y, dz1 = pz[i] - gz.y;
            float dx2 = px[i] - gx.z, dy2 = py[i] - gy.z, dz2 = pz[i] - gz.z;
            float dx3 = px[i] - gx.w, dy3 = py[i] - gy.w, dz3 = pz[i] - gz.w;
            float s0, s1, s2, s3, d0, d1, d2, d3;
            asm("v_add_f32_e64 %0, |%1|, |%2|" : "=v"(s0) : "v"(dx0), "v"(dy0));
            asm("v_add_f32_e64 %0, %1, |%2|"   : "=v"(d0) : "v"(s0),  "v"(dz0));
            asm("v_add_f32_e64 %0, |%1|, |%2|" : "=v"(s1) : "v"(dx1), "v"(dy1));
            asm("v_add_f32_e64 %0, %1, |%2|"   : "=v"(d1) : "v"(s1),  "v"(dz1));
            asm("v_add_f32_e64 %0, |%1|, |%2|" : "=v"(s2) : "v"(dx2), "v"(dy2));
            asm("v_add_f32_e64 %0, %1, |%2|"   : "=v"(d2) : "v"(s2),  "v"(dz2));
            asm("v_add_f32_e64 %0, |%1|, |%2|" : "=v"(s3) : "v"(dx3), "v"(dy3));
            asm("v_add_f32_e64 %0, %1, |%2|"   : "=v"(d3) : "v"(s3),  "v"(dz3));
            asm("v_min3_f32 %0, %0, %1, %2"    : "+v"(mn[i]) : "v"(d0), "v"(d1));
            asm("v_min3_f32 %0, %0, %1, %2"    : "+v"(mn[i]) : "v"(d2), "v"(d3));
        }
        gx = nx; gy = ny; gz = nz;
    }

    // partial[mc][dir][b][n] — coalesced stores (N==M assumed for stride).
    float* outp = partial + (((size_t)mc * 2 + dir) * B + b) * N;
#pragma unroll
    for (int i = 0; i < PTS; ++i) outp[n[i]] = mn[i];
}

__global__ __launch_bounds__(256) void chamfer_reduce_kernel(
    const float* __restrict__ partial, float* __restrict__ out,
    int Q, float inv) {
    const int qidx = blockIdx.x * 256 + threadIdx.x;
    float mn = FLT_MAX;
#pragma unroll
    for (int mc = 0; mc < 32; ++mc)   // nmc == 32 for N==M==4096, MC==128
        mn = fminf(mn, partial[(size_t)mc * Q + qidx]);
    float v = mn * inv;

    // wave-64 shuffle reduce, then cross-wave via LDS
    for (int off = 32; off > 0; off >>= 1) v += __shfl_down(v, off, 64);
    __shared__ float red[4];
    const int lane = threadIdx.x & 63, w = threadIdx.x >> 6;
    if (lane == 0) red[w] = v;
    __syncthreads();
    if (threadIdx.x == 0)
        atomicAdd(out, red[0] + red[1] + red[2] + red[3]);
}

extern "C" void kernel_launch(void* const* d_in, const int* in_sizes, int n_in,
                              void* d_out, int out_size, void* d_ws, size_t ws_size,
                              hipStream_t stream) {
    const float* pred = (const float*)d_in[0];
    const float* gt   = (const float*)d_in[1];
    float* out = (float*)d_out;

    const int B = 4;
    const int N = in_sizes[0] / (B * 3);   // 4096
    const int M = in_sizes[1] / (B * 3);   // 4096

    float* partial = (float*)d_ws;          // [32][2][B][N] floats = 4 MB
    const int Q = 2 * B * N;                // 32768

    dim3 grid((N / NC) * (M / MC), B, 2);   // 64 x 4 x 2 = 512 blocks
    chamfer_partial_kernel<<<grid, TPB, 0, stream>>>(pred, gt, partial, out, B, N, M);

    // mean scale: 1/(B*N) for dir0, 1/(B*M) for dir1 — equal since N==M.
    chamfer_reduce_kernel<<<Q / 256, 256, 0, stream>>>(
        partial, out, Q, 1.0f / (float)(B * N));
}